// Round 6
// baseline (117.137 us; speedup 1.0000x reference)
//
#include <hip/hip_runtime.h>
#include <cstdint>
#include <cstddef>

// ---------------------------------------------------------------------------
// Multi-scale region distillation loss — R6: contiguous-1KB streaming.
//
// Per pixel (NCHW channel reduction):
//   Zn = sum_c exp(xn_c), Zo = sum_c exp(xo_c), S = sum_c exp(xn_c)*(xn_c-xo_c)
//   kl = S/Zn - log(Zn) + log(Zo)
// Then per-class mean per scale, coef-weighted, scale weights 1..4.
//
// k1 geometry: every block = 256-pixel window x 256 channels (512 KB), 4
// waves each take a 64-channel quarter over the SAME window. Lane i owns
// pixels 4i..4i+3 for every channel -> each load is a contiguous 1 KB line
// (64 lanes x float4). Registers-only main loop; 4-way LDS combine at end.
//   s0 (C=256):  in-block finish (kl + class bins).       512 blocks
//   s1 (C=512):  2 ch-splits -> global partials.          256 blocks
//   s2 (C=1024): 4 ch-splits -> global partials.          128 blocks
//   s3 (C=2048): 8 ch-splits -> global partials.           64 blocks
// k2 finishes s1/s2/s3 pixels (43008); k3 reduces class bins.
//
// Input order (verified R3): d_in = {labels, fn0, fo0, fn1, fo1, ...} —
// resolved defensively from in_sizes.
// ws: 43008*3 partials + 2*128 bins = 129280 floats (517 KB).
// ---------------------------------------------------------------------------

#define TPB 256
#define NPART 43008              // s1(32768) + s2(8192) + s3(2048) pixels
#define WS_ZERO_FLOATS (NPART * 3 + 256)

#define LD4(p) (*(const float4*)(p))

__global__ __launch_bounds__(TPB)
void k0_zero(float* __restrict__ ws) {
    const int i = blockIdx.x * TPB + threadIdx.x;
    if (i < WS_ZERO_FLOATS) ws[i] = 0.f;
}

// C channels, HW pixels/img, W width, F label stride, FIN: finish in-block.
template<int C, int HW, int W, int F, bool FIN>
__device__ __forceinline__ void scale_pass(const float* __restrict__ fn,
                                           const float* __restrict__ fo,
                                           const int* __restrict__ labels,
                                           int ncls, int pOff,
                                           float* __restrict__ pZn,
                                           float* __restrict__ pZo,
                                           float* __restrict__ pS,
                                           float* __restrict__ clsSum,
                                           float* __restrict__ clsCnt,
                                           float* smem, int lb) {
    constexpr int NPXB = (8 * HW) / 256;    // pixel windows per scale

    const int tid  = threadIdx.x;
    const int wid  = tid >> 6;
    const int lane = tid & 63;
    const int pxb = lb % NPXB;
    const int cb  = lb / NPXB;

    const int q0  = pxb * 256;              // first pixel of window (in scale)
    const int b   = q0 / HW;                // 256 | HW -> window in one image
    const int px0 = q0 % HW;
    const int c0  = cb * 256 + wid * 64;    // this wave's channel base

    // lane's contiguous float4 slot; whole wave = 1KB contiguous per channel
    const float* pn = fn + ((size_t)b * C + c0) * HW + px0 + 4 * lane;
    const float* po = fo + ((size_t)b * C + c0) * HW + px0 + 4 * lane;

    float zn0=0.f,zn1=0.f,zn2=0.f,zn3=0.f;
    float zo0=0.f,zo1=0.f,zo2=0.f,zo3=0.f;
    float sA0=0.f,sA1=0.f,sA2=0.f,sA3=0.f;

#define ACC(nv, ov, i_) { const float en_=__expf(nv), eo_=__expf(ov);          \
        zn##i_ += en_; zo##i_ += eo_; sA##i_ += en_ * ((nv) - (ov)); }
#define ACCQ(a_, b_) { ACC(a_.x,b_.x,0) ACC(a_.y,b_.y,1)                        \
                       ACC(a_.z,b_.z,2) ACC(a_.w,b_.w,3) }

    for (int k = 0; k < 64; k += 4) {
        const size_t o0 = (size_t)(k + 0) * HW;
        const size_t o1 = (size_t)(k + 1) * HW;
        const size_t o2 = (size_t)(k + 2) * HW;
        const size_t o3 = (size_t)(k + 3) * HW;
        const float4 xn0 = LD4(pn + o0), xn1 = LD4(pn + o1);
        const float4 xn2 = LD4(pn + o2), xn3 = LD4(pn + o3);
        const float4 xo0 = LD4(po + o0), xo1 = LD4(po + o1);
        const float4 xo2 = LD4(po + o2), xo3 = LD4(po + o3);
        ACCQ(xn0, xo0) ACCQ(xn1, xo1) ACCQ(xn2, xo2) ACCQ(xn3, xo3)
    }
#undef ACC
#undef ACCQ

    // ---- 4-way cross-wave combine in LDS: lacc[4][768] ----
    float* lacc = smem;
    float* r = lacc + wid * 768 + lane * 12;   // [wid][(4*lane+j)*3 + comp]
    r[0]=zn0; r[1]=zo0; r[2]=sA0;
    r[3]=zn1; r[4]=zo1; r[5]=sA1;
    r[6]=zn2; r[7]=zo2; r[8]=sA2;
    r[9]=zn3; r[10]=zo3; r[11]=sA3;
    float* ls = smem + 3072;
    float* lc = smem + 3104;
    if (tid < 32) { ls[tid] = 0.f; lc[tid] = 0.f; }
    __syncthreads();

    // thread t owns pixel t of the window
    float zn = 0.f, zo = 0.f, s = 0.f;
    #pragma unroll
    for (int w = 0; w < 4; ++w) {
        const float* rr = lacc + w * 768 + tid * 3;
        zn += rr[0]; zo += rr[1]; s += rr[2];
    }

    if (FIN) {
        const float kl = s / zn - logf(zn) + logf(zo);
        const int pp = px0 + tid;
        const int h = pp / W, w = pp % W;
        const int lab = labels[b * 262144 + (h * F) * 512 + (w * F)];
        if ((unsigned)lab < (unsigned)ncls) {
            atomicAdd(&ls[lab], kl);
            atomicAdd(&lc[lab], 1.0f);
        }
        __syncthreads();
        if (tid < 32) {
            const float cv = lc[tid];
            if (cv != 0.f) {
                atomicAdd(&clsSum[tid], ls[tid]);   // scale 0 -> row 0
                atomicAdd(&clsCnt[tid], cv);
            }
        }
    } else {
        const int g = pOff + q0 + tid;
        atomicAdd(&pZn[g], zn);
        atomicAdd(&pZo[g], zo);
        atomicAdd(&pS[g],  s);
    }
}

// Grid: 960 identical 512KB blocks.
//   [0,512):   s0 FIN
//   [512,768): s1 partials (pOff 0)
//   [768,896): s2 partials (pOff 32768)
//   [896,960): s3 partials (pOff 40960)
__global__ __launch_bounds__(TPB, 4)
void k1_fused(const float* __restrict__ fn0, const float* __restrict__ fo0,
              const float* __restrict__ fn1, const float* __restrict__ fo1,
              const float* __restrict__ fn2, const float* __restrict__ fo2,
              const float* __restrict__ fn3, const float* __restrict__ fo3,
              const int* __restrict__ labels, const int* __restrict__ pNC,
              float* __restrict__ pZn, float* __restrict__ pZo,
              float* __restrict__ pS,
              float* __restrict__ clsSum, float* __restrict__ clsCnt) {
    __shared__ float smem[3136];            // 12.25 KB
    const int ncls = *pNC;
    const int bb = blockIdx.x;
    if (bb < 512) {
        scale_pass<256, 16384, 128, 4, true>(fn0, fo0, labels, ncls, 0,
            pZn, pZo, pS, clsSum, clsCnt, smem, bb);
    } else if (bb < 768) {
        scale_pass<512, 4096, 64, 8, false>(fn1, fo1, labels, ncls, 0,
            pZn, pZo, pS, clsSum, clsCnt, smem, bb - 512);
    } else if (bb < 896) {
        scale_pass<1024, 1024, 32, 16, false>(fn2, fo2, labels, ncls, 32768,
            pZn, pZo, pS, clsSum, clsCnt, smem, bb - 768);
    } else {
        scale_pass<2048, 256, 16, 32, false>(fn3, fo3, labels, ncls, 40960,
            pZn, pZo, pS, clsSum, clsCnt, smem, bb - 896);
    }
}

// finish s1/s2/s3: kl from partials + class bins. 168 blocks x 256.
__global__ __launch_bounds__(TPB)
void k2_finish(const int* __restrict__ labels,
               const float* __restrict__ pZn, const float* __restrict__ pZo,
               const float* __restrict__ pS,
               float* __restrict__ clsSum, float* __restrict__ clsCnt,
               const int* __restrict__ pNC) {
    const int ncls = *pNC;
    const int t = threadIdx.x;
    const int i = blockIdx.x * TPB + t;     // [0, 43008)

    int sc, q, HW, W, F;
    if (i < 32768)      { sc = 1; q = i;          HW = 4096; W = 64; F = 8;  }
    else if (i < 40960) { sc = 2; q = i - 32768;  HW = 1024; W = 32; F = 16; }
    else                { sc = 3; q = i - 40960;  HW = 256;  W = 16; F = 32; }

    __shared__ float ls[32], lc[32];
    if (t < 32) { ls[t] = 0.f; lc[t] = 0.f; }
    __syncthreads();

    const float zn = pZn[i];
    const float zo = pZo[i];
    const float s  = pS[i];
    const float kl = s / zn - logf(zn) + logf(zo);
    const int b  = q / HW;
    const int pp = q % HW;
    const int h  = pp / W;
    const int w  = pp % W;
    const int lab = labels[b * 262144 + (h * F) * 512 + (w * F)];
    if ((unsigned)lab < (unsigned)ncls) {
        atomicAdd(&ls[lab], kl);
        atomicAdd(&lc[lab], 1.0f);
    }
    __syncthreads();
    if (t < 32 && lc[t] != 0.f) {
        atomicAdd(&clsSum[sc * 32 + t], ls[t]);
        atomicAdd(&clsCnt[sc * 32 + t], lc[t]);
    }
}

__global__ void k3_finalize(const float* __restrict__ clsSum,
                            const float* __restrict__ clsCnt,
                            const int* __restrict__ pNC,
                            const int* __restrict__ pNOC,
                            float* __restrict__ out) {
    const int t = threadIdx.x;              // 64 threads, one wave
    const int ncls = *pNC;
    const int nold = *pNOC;
    float acc = 0.f;
    for (int i = t; i < 128; i += 64) {
        const int s_ = i / 32;
        const int c  = i % 32;
        if (c < ncls) {
            const float cnt = clsCnt[i];
            const float sum = clsSum[i];
            const float mean = (cnt > 0.f) ? (sum / cnt) : 0.f;
            const float coef = (c == 0) ? (float)nold / (float)ncls
                                        : ((c <= nold) ? 1.f : 0.f);
            acc += (float)(s_ + 1) * coef * mean;   // WEIGHTS = 1,2,3,4
        }
    }
    #pragma unroll
    for (int off = 32; off > 0; off >>= 1) acc += __shfl_down(acc, off, 64);
    if (t == 0) out[0] = acc;
}

extern "C" void kernel_launch(void* const* d_in, const int* in_sizes, int n_in,
                              void* d_out, int out_size, void* d_ws, size_t ws_size,
                              hipStream_t stream) {
    const int* labels = (const int*)d_in[0];
    const float* fn[4];
    const float* fo[4];

    if (in_sizes[2] == in_sizes[1]) {       // interleaved (expected)
        fn[0] = (const float*)d_in[1]; fo[0] = (const float*)d_in[2];
        fn[1] = (const float*)d_in[3]; fo[1] = (const float*)d_in[4];
        fn[2] = (const float*)d_in[5]; fo[2] = (const float*)d_in[6];
        fn[3] = (const float*)d_in[7]; fo[3] = (const float*)d_in[8];
    } else {                                 // grouped (reference signature)
        fn[0] = (const float*)d_in[1]; fn[1] = (const float*)d_in[2];
        fn[2] = (const float*)d_in[3]; fn[3] = (const float*)d_in[4];
        fo[0] = (const float*)d_in[5]; fo[1] = (const float*)d_in[6];
        fo[2] = (const float*)d_in[7]; fo[3] = (const float*)d_in[8];
    }
    const int* pNC  = (const int*)d_in[9];
    const int* pNOC = (const int*)d_in[10];

    float* ws = (float*)d_ws;
    float* pZn = ws;                        // 43008
    float* pZo = ws + NPART;                // 43008
    float* pS  = ws + 2 * (size_t)NPART;    // 43008
    float* clsSum = ws + 3 * (size_t)NPART; // 128
    float* clsCnt = clsSum + 128;           // 128

    k0_zero<<<(WS_ZERO_FLOATS + TPB - 1) / TPB, TPB, 0, stream>>>(ws);
    k1_fused<<<960, TPB, 0, stream>>>(fn[0], fo[0], fn[1], fo[1],
                                      fn[2], fo[2], fn[3], fo[3],
                                      labels, pNC, pZn, pZo, pS, clsSum, clsCnt);
    k2_finish<<<NPART / TPB, TPB, 0, stream>>>(labels, pZn, pZo, pS,
                                               clsSum, clsCnt, pNC);
    k3_finalize<<<1, 64, 0, stream>>>(clsSum, clsCnt, pNC, pNOC, (float*)d_out);
}

// Round 7
// 110.346 us; speedup vs baseline: 1.0615x; 1.0615x over previous
//
#include <hip/hip_runtime.h>
#include <cstdint>
#include <cstddef>

// ---------------------------------------------------------------------------
// Multi-scale region distillation loss — R7: R4's best-measured k1 +
// minimized overhead (3 kernels, no s3 atomics, 256-float zero).
//
// Per pixel (NCHW channel reduction):
//   Zn = sum_c exp(xn_c), Zo = sum_c exp(xo_c), S = sum_c exp(xn_c)*(xn_c-xo_c)
//   kl = S/Zn - log(Zn) + log(Zo)
// Then per-class mean per scale, coef-weighted, scale weights 1..4.
//
// k1 grid: 2048 uniform blocks (8/CU):
//   s0 [0,1024):    128px x 256ch   (256 KB)
//   s1 [1024,1536):  64px x 512ch   (256 KB)
//   s2 [1536,1792):  32px x 1024ch  (256 KB)
//   s3 [1792,2048):  32px x 512ch, 4-way ch-split -> slice WRITES (64 KB)
// k3: single block — s3 slice-sum + kl + bins, then final weighted reduce.
//
// Input order (verified R3): d_in = {labels, fn0, fo0, fn1, fo1, ...} —
// resolved defensively from in_sizes.
// ws: s3 slices 4*2048*3 = 24576 floats + 256 class-bin floats.
// ---------------------------------------------------------------------------

#define TPB 256
#define BINS_OFF 24576   // float offset of clsSum in ws

__global__ __launch_bounds__(TPB)
void k0_zero(float* __restrict__ bins) {
    bins[threadIdx.x] = 0.f;   // 256 floats: clsSum[128] + clsCnt[128]
}

// C channels, HW px/img, W width, F label stride, PIXT pixel-quads/block,
// CG channel groups (PIXT*CG==TPB), SPLIT ch-split blocks (slice writes).
template<int C, int HW, int W, int F, int PIXT, int CG, int SPLIT>
__device__ __forceinline__ void scale_pass(const float* __restrict__ fn,
                                           const float* __restrict__ fo,
                                           const int* __restrict__ labels,
                                           int ncls, int sc,
                                           float* __restrict__ pPart,
                                           float* __restrict__ clsSum,
                                           float* __restrict__ clsCnt,
                                           float* red, float* ls, float* lc,
                                           int lb) {
    constexpr int PIXB = 4 * PIXT;          // pixels per block
    constexpr int NPB  = (8 * HW) / PIXB;   // pixel-blocks per scale
    constexpr int CH   = C / SPLIT;         // channels this block handles
    constexpr int IT   = CH / CG;           // channel iters per thread (even)

    const int t  = threadIdx.x;
    const int tx = t % PIXT;
    const int ty = t / PIXT;
    const int pb = lb % NPB;
    const int sp = lb / NPB;

    const int q0 = pb * PIXB;               // first pixel (within scale)
    const int b  = q0 / HW;                 // PIXB | HW -> block in one image
    const int p  = (q0 % HW) + tx * 4;
    const size_t base = (size_t)b * C * HW + p;
    const float* bn = fn + base;
    const float* bo = fo + base;
    const int cbase = sp * CH;

    float zn0=0.f, zn1=0.f, zn2=0.f, zn3=0.f;
    float zo0=0.f, zo1=0.f, zo2=0.f, zo3=0.f;
    float s0 =0.f, s1 =0.f, s2 =0.f, s3 =0.f;

    // 2x unroll: issue all four 16B loads before compute.
    for (int k = 0; k < IT; k += 2) {
        const int c0 = cbase + k * CG + ty;
        const int c1 = c0 + CG;
        const float4 xn0 = *(const float4*)(bn + (size_t)c0 * HW);
        const float4 xo0 = *(const float4*)(bo + (size_t)c0 * HW);
        const float4 xn1 = *(const float4*)(bn + (size_t)c1 * HW);
        const float4 xo1 = *(const float4*)(bo + (size_t)c1 * HW);
        float en, eo;
        en = __expf(xn0.x); eo = __expf(xo0.x);
        zn0 += en; zo0 += eo; s0 += en * (xn0.x - xo0.x);
        en = __expf(xn0.y); eo = __expf(xo0.y);
        zn1 += en; zo1 += eo; s1 += en * (xn0.y - xo0.y);
        en = __expf(xn0.z); eo = __expf(xo0.z);
        zn2 += en; zo2 += eo; s2 += en * (xn0.z - xo0.z);
        en = __expf(xn0.w); eo = __expf(xo0.w);
        zn3 += en; zo3 += eo; s3 += en * (xn0.w - xo0.w);
        en = __expf(xn1.x); eo = __expf(xo1.x);
        zn0 += en; zo0 += eo; s0 += en * (xn1.x - xo1.x);
        en = __expf(xn1.y); eo = __expf(xo1.y);
        zn1 += en; zo1 += eo; s1 += en * (xn1.y - xo1.y);
        en = __expf(xn1.z); eo = __expf(xo1.z);
        zn2 += en; zo2 += eo; s2 += en * (xn1.z - xo1.z);
        en = __expf(xn1.w); eo = __expf(xo1.w);
        zn3 += en; zo3 += eo; s3 += en * (xn1.w - xo1.w);
    }

    // stash per-thread partials: red[(ty*PIXT+tx)*12 + j*3 + comp]
    float* r = red + (size_t)(ty * PIXT + tx) * 12;
    r[0]  = zn0; r[1]  = zo0; r[2]  = s0;
    r[3]  = zn1; r[4]  = zo1; r[5]  = s1;
    r[6]  = zn2; r[7]  = zo2; r[8]  = s2;
    r[9]  = zn3; r[10] = zo3; r[11] = s3;
    if (t < 32) { ls[t] = 0.f; lc[t] = 0.f; }
    __syncthreads();

    // per-pixel combine across CG channel groups
    for (int i = t; i < PIXB; i += TPB) {
        const int txi = i >> 2;
        const int j   = i & 3;
        float zn = 0.f, zo = 0.f, s = 0.f;
        #pragma unroll
        for (int g = 0; g < CG; ++g) {
            const float* rr = red + (size_t)(g * PIXT + txi) * 12 + j * 3;
            zn += rr[0]; zo += rr[1]; s += rr[2];
        }
        const int q = q0 + i;               // pixel index within scale
        if (SPLIT == 1) {
            const float kl = s / zn - logf(zn) + logf(zo);
            const int pp = q % HW;
            const int h  = pp / W;
            const int w  = pp % W;
            const int lab = labels[b * 262144 + (h * F) * 512 + (w * F)];
            if ((unsigned)lab < (unsigned)ncls) {
                atomicAdd(&ls[lab], kl);
                atomicAdd(&lc[lab], 1.0f);
            }
        } else {
            // disjoint slice write — no atomics, no pre-zero needed
            float* w_ = pPart + ((size_t)sp * 2048 + q) * 3;
            w_[0] = zn; w_[1] = zo; w_[2] = s;
        }
    }

    if (SPLIT == 1) {
        __syncthreads();
        if (t < 32) {
            const float cv = lc[t];
            if (cv != 0.f) {
                atomicAdd(&clsSum[sc * 32 + t], ls[t]);
                atomicAdd(&clsCnt[sc * 32 + t], cv);
            }
        }
    }
}

__global__ __launch_bounds__(TPB, 8)
void k1_fused(const float* __restrict__ fn0, const float* __restrict__ fo0,
              const float* __restrict__ fn1, const float* __restrict__ fo1,
              const float* __restrict__ fn2, const float* __restrict__ fo2,
              const float* __restrict__ fn3, const float* __restrict__ fo3,
              const int* __restrict__ labels, const int* __restrict__ pNC,
              float* __restrict__ pPart,
              float* __restrict__ clsSum, float* __restrict__ clsCnt) {
    __shared__ float red[TPB * 12];
    __shared__ float ls[32], lc[32];
    const int ncls = *pNC;
    const int bb = blockIdx.x;
    if (bb < 1024) {
        scale_pass<256, 16384, 128, 4, 32, 8, 1>(fn0, fo0, labels, ncls, 0,
            pPart, clsSum, clsCnt, red, ls, lc, bb);
    } else if (bb < 1536) {
        scale_pass<512, 4096, 64, 8, 16, 16, 1>(fn1, fo1, labels, ncls, 1,
            pPart, clsSum, clsCnt, red, ls, lc, bb - 1024);
    } else if (bb < 1792) {
        scale_pass<1024, 1024, 32, 16, 8, 32, 1>(fn2, fo2, labels, ncls, 2,
            pPart, clsSum, clsCnt, red, ls, lc, bb - 1536);
    } else {
        scale_pass<2048, 256, 16, 32, 8, 32, 4>(fn3, fo3, labels, ncls, 3,
            pPart, clsSum, clsCnt, red, ls, lc, bb - 1792);
    }
}

// single block: finish s3 (slice-sum -> kl -> bins) + final weighted reduce
__global__ __launch_bounds__(TPB)
void k3_final(const int* __restrict__ labels,
              const float* __restrict__ pPart,
              const float* __restrict__ clsSum, const float* __restrict__ clsCnt,
              const int* __restrict__ pNC, const int* __restrict__ pNOC,
              float* __restrict__ out) {
    const int t = threadIdx.x;
    const int ncls = *pNC;
    const int nold = *pNOC;
    __shared__ float ls[32], lc[32], redf[TPB];
    if (t < 32) { ls[t] = 0.f; lc[t] = 0.f; }
    __syncthreads();

    // s3: 2048 pixels, sum 4 channel-split slices
    for (int i = t; i < 2048; i += TPB) {
        float zn = 0.f, zo = 0.f, s = 0.f;
        #pragma unroll
        for (int sp = 0; sp < 4; ++sp) {
            const float* r = pPart + ((size_t)sp * 2048 + i) * 3;
            zn += r[0]; zo += r[1]; s += r[2];
        }
        const float kl = s / zn - logf(zn) + logf(zo);
        const int b  = i / 256;
        const int pp = i % 256;
        const int h  = pp / 16;
        const int w  = pp % 16;
        const int lab = labels[b * 262144 + (h * 32) * 512 + (w * 32)];
        if ((unsigned)lab < (unsigned)ncls) {
            atomicAdd(&ls[lab], kl);
            atomicAdd(&lc[lab], 1.0f);
        }
    }
    __syncthreads();

    // combine: scales 0-2 from global bins, scale 3 from LDS bins
    float acc = 0.f;
    if (t < 128) {
        const int sc = t / 32;
        const int c  = t % 32;
        if (c < ncls) {
            const float sum = (sc < 3) ? clsSum[sc * 32 + c] : ls[c];
            const float cnt = (sc < 3) ? clsCnt[sc * 32 + c] : lc[c];
            const float mean = (cnt > 0.f) ? (sum / cnt) : 0.f;
            const float coef = (c == 0) ? (float)nold / (float)ncls
                                        : ((c <= nold) ? 1.f : 0.f);
            acc = (float)(sc + 1) * coef * mean;    // WEIGHTS = 1,2,3,4
        }
    }
    redf[t] = acc;
    __syncthreads();
    if (t == 0) {
        float total = 0.f;
        for (int i = 0; i < 128; ++i) total += redf[i];
        out[0] = total;
    }
}

extern "C" void kernel_launch(void* const* d_in, const int* in_sizes, int n_in,
                              void* d_out, int out_size, void* d_ws, size_t ws_size,
                              hipStream_t stream) {
    const int* labels = (const int*)d_in[0];
    const float* fn[4];
    const float* fo[4];

    if (in_sizes[2] == in_sizes[1]) {       // interleaved (expected)
        fn[0] = (const float*)d_in[1]; fo[0] = (const float*)d_in[2];
        fn[1] = (const float*)d_in[3]; fo[1] = (const float*)d_in[4];
        fn[2] = (const float*)d_in[5]; fo[2] = (const float*)d_in[6];
        fn[3] = (const float*)d_in[7]; fo[3] = (const float*)d_in[8];
    } else {                                 // grouped (reference signature)
        fn[0] = (const float*)d_in[1]; fn[1] = (const float*)d_in[2];
        fn[2] = (const float*)d_in[3]; fn[3] = (const float*)d_in[4];
        fo[0] = (const float*)d_in[5]; fo[1] = (const float*)d_in[6];
        fo[2] = (const float*)d_in[7]; fo[3] = (const float*)d_in[8];
    }
    const int* pNC  = (const int*)d_in[9];
    const int* pNOC = (const int*)d_in[10];

    float* ws = (float*)d_ws;
    float* pPart  = ws;                     // 4*2048*3 = 24576 floats
    float* clsSum = ws + BINS_OFF;          // 128
    float* clsCnt = clsSum + 128;           // 128

    k0_zero<<<1, TPB, 0, stream>>>(clsSum);
    k1_fused<<<2048, TPB, 0, stream>>>(fn[0], fo[0], fn[1], fo[1],
                                       fn[2], fo[2], fn[3], fo[3],
                                       labels, pNC, pPart, clsSum, clsCnt);
    k3_final<<<1, TPB, 0, stream>>>(labels, pPart, clsSum, clsCnt,
                                    pNC, pNOC, (float*)d_out);
}

// Round 8
// 108.141 us; speedup vs baseline: 1.0832x; 1.0204x over previous
//
#include <hip/hip_runtime.h>
#include <cstdint>
#include <cstddef>

// ---------------------------------------------------------------------------
// Multi-scale region distillation loss — R8: R4's best-measured k1 verbatim,
// leanest ancillary chain (256-float zero, disjoint s3 slice writes,
// parallel 8-block s3 finisher, 1-wave final reduce).
//
// Per pixel (NCHW channel reduction):
//   Zn = sum_c exp(xn_c), Zo = sum_c exp(xo_c), S = sum_c exp(xn_c)*(xn_c-xo_c)
//   kl = S/Zn - log(Zn) + log(Zo)
// Then per-class mean per scale, coef-weighted, scale weights 1..4.
//
// k1 grid: 2048 uniform blocks (8/CU):
//   s0 [0,1024):    128px x 256ch   (256 KB)
//   s1 [1024,1536):  64px x 512ch   (256 KB)
//   s2 [1536,1792):  32px x 1024ch  (256 KB)
//   s3 [1792,2048):  32px x 512ch, 4-way ch-split -> disjoint slice writes
//
// Input order (verified R3): d_in = {labels, fn0, fo0, fn1, fo1, ...} —
// resolved defensively from in_sizes.
// ws: s3 slices 4*2048*3 = 24576 floats + 256 class-bin floats.
// ---------------------------------------------------------------------------

#define TPB 256
#define P3 2048
#define BINS_OFF 24576   // float offset of clsSum in ws

__global__ __launch_bounds__(TPB)
void k0_zero(float* __restrict__ bins) {
    bins[threadIdx.x] = 0.f;   // 256 floats: clsSum[128] + clsCnt[128]
}

// C channels, HW px/img, W width, F label stride, PIXT pixel-quads/block,
// CG channel groups (PIXT*CG==TPB), SPLIT ch-split blocks (slice writes).
template<int C, int HW, int W, int F, int PIXT, int CG, int SPLIT>
__device__ __forceinline__ void scale_pass(const float* __restrict__ fn,
                                           const float* __restrict__ fo,
                                           const int* __restrict__ labels,
                                           int ncls, int sc,
                                           float* __restrict__ pPart,
                                           float* __restrict__ clsSum,
                                           float* __restrict__ clsCnt,
                                           float* red, float* ls, float* lc,
                                           int lb) {
    constexpr int PIXB = 4 * PIXT;          // pixels per block
    constexpr int NPB  = (8 * HW) / PIXB;   // pixel-blocks per scale
    constexpr int CH   = C / SPLIT;         // channels this block handles
    constexpr int IT   = CH / CG;           // channel iters per thread (even)

    const int t  = threadIdx.x;
    const int tx = t % PIXT;
    const int ty = t / PIXT;
    const int pb = lb % NPB;
    const int sp = lb / NPB;

    const int q0 = pb * PIXB;               // first pixel (within scale)
    const int b  = q0 / HW;                 // PIXB | HW -> block in one image
    const int p  = (q0 % HW) + tx * 4;
    const size_t base = (size_t)b * C * HW + p;
    const float* bn = fn + base;
    const float* bo = fo + base;
    const int cbase = sp * CH;

    float zn0=0.f, zn1=0.f, zn2=0.f, zn3=0.f;
    float zo0=0.f, zo1=0.f, zo2=0.f, zo3=0.f;
    float s0 =0.f, s1 =0.f, s2 =0.f, s3 =0.f;

    // 2x unroll: issue all four 16B loads before compute.
    for (int k = 0; k < IT; k += 2) {
        const int c0 = cbase + k * CG + ty;
        const int c1 = c0 + CG;
        const float4 xn0 = *(const float4*)(bn + (size_t)c0 * HW);
        const float4 xo0 = *(const float4*)(bo + (size_t)c0 * HW);
        const float4 xn1 = *(const float4*)(bn + (size_t)c1 * HW);
        const float4 xo1 = *(const float4*)(bo + (size_t)c1 * HW);
        float en, eo;
        en = __expf(xn0.x); eo = __expf(xo0.x);
        zn0 += en; zo0 += eo; s0 += en * (xn0.x - xo0.x);
        en = __expf(xn0.y); eo = __expf(xo0.y);
        zn1 += en; zo1 += eo; s1 += en * (xn0.y - xo0.y);
        en = __expf(xn0.z); eo = __expf(xo0.z);
        zn2 += en; zo2 += eo; s2 += en * (xn0.z - xo0.z);
        en = __expf(xn0.w); eo = __expf(xo0.w);
        zn3 += en; zo3 += eo; s3 += en * (xn0.w - xo0.w);
        en = __expf(xn1.x); eo = __expf(xo1.x);
        zn0 += en; zo0 += eo; s0 += en * (xn1.x - xo1.x);
        en = __expf(xn1.y); eo = __expf(xo1.y);
        zn1 += en; zo1 += eo; s1 += en * (xn1.y - xo1.y);
        en = __expf(xn1.z); eo = __expf(xo1.z);
        zn2 += en; zo2 += eo; s2 += en * (xn1.z - xo1.z);
        en = __expf(xn1.w); eo = __expf(xo1.w);
        zn3 += en; zo3 += eo; s3 += en * (xn1.w - xo1.w);
    }

    // stash per-thread partials: red[(ty*PIXT+tx)*12 + j*3 + comp]
    float* r = red + (size_t)(ty * PIXT + tx) * 12;
    r[0]  = zn0; r[1]  = zo0; r[2]  = s0;
    r[3]  = zn1; r[4]  = zo1; r[5]  = s1;
    r[6]  = zn2; r[7]  = zo2; r[8]  = s2;
    r[9]  = zn3; r[10] = zo3; r[11] = s3;
    if (t < 32) { ls[t] = 0.f; lc[t] = 0.f; }
    __syncthreads();

    // per-pixel combine across CG channel groups
    for (int i = t; i < PIXB; i += TPB) {
        const int txi = i >> 2;
        const int j   = i & 3;
        float zn = 0.f, zo = 0.f, s = 0.f;
        #pragma unroll
        for (int g = 0; g < CG; ++g) {
            const float* rr = red + (size_t)(g * PIXT + txi) * 12 + j * 3;
            zn += rr[0]; zo += rr[1]; s += rr[2];
        }
        const int q = q0 + i;               // pixel index within scale
        if (SPLIT == 1) {
            const float kl = s / zn - logf(zn) + logf(zo);
            const int pp = q % HW;
            const int h  = pp / W;
            const int w  = pp % W;
            const int lab = labels[b * 262144 + (h * F) * 512 + (w * F)];
            if ((unsigned)lab < (unsigned)ncls) {
                atomicAdd(&ls[lab], kl);
                atomicAdd(&lc[lab], 1.0f);
            }
        } else {
            // disjoint slice write — no atomics, no pre-zero needed
            float* w_ = pPart + ((size_t)sp * P3 + q) * 3;
            w_[0] = zn; w_[1] = zo; w_[2] = s;
        }
    }

    if (SPLIT == 1) {
        __syncthreads();
        if (t < 32) {
            const float cv = lc[t];
            if (cv != 0.f) {
                atomicAdd(&clsSum[sc * 32 + t], ls[t]);
                atomicAdd(&clsCnt[sc * 32 + t], cv);
            }
        }
    }
}

__global__ __launch_bounds__(TPB, 8)
void k1_fused(const float* __restrict__ fn0, const float* __restrict__ fo0,
              const float* __restrict__ fn1, const float* __restrict__ fo1,
              const float* __restrict__ fn2, const float* __restrict__ fo2,
              const float* __restrict__ fn3, const float* __restrict__ fo3,
              const int* __restrict__ labels, const int* __restrict__ pNC,
              float* __restrict__ pPart,
              float* __restrict__ clsSum, float* __restrict__ clsCnt) {
    __shared__ float red[TPB * 12];
    __shared__ float ls[32], lc[32];
    const int ncls = *pNC;
    const int bb = blockIdx.x;
    if (bb < 1024) {
        scale_pass<256, 16384, 128, 4, 32, 8, 1>(fn0, fo0, labels, ncls, 0,
            pPart, clsSum, clsCnt, red, ls, lc, bb);
    } else if (bb < 1536) {
        scale_pass<512, 4096, 64, 8, 16, 16, 1>(fn1, fo1, labels, ncls, 1,
            pPart, clsSum, clsCnt, red, ls, lc, bb - 1024);
    } else if (bb < 1792) {
        scale_pass<1024, 1024, 32, 16, 8, 32, 1>(fn2, fo2, labels, ncls, 2,
            pPart, clsSum, clsCnt, red, ls, lc, bb - 1536);
    } else {
        scale_pass<2048, 256, 16, 32, 8, 32, 4>(fn3, fo3, labels, ncls, 3,
            pPart, clsSum, clsCnt, red, ls, lc, bb - 1792);
    }
}

// scale-3 finish: sum 4 channel-split slices -> kl -> class bins. 8 blocks.
__global__ __launch_bounds__(TPB)
void k2_scale3(const int* __restrict__ labels,
               const float* __restrict__ pPart,
               float* __restrict__ clsSum, float* __restrict__ clsCnt,
               const int* __restrict__ pNC) {
    const int ncls = *pNC;
    const int t = threadIdx.x;
    const int q = blockIdx.x * TPB + t;     // [0, 2048)
    __shared__ float ls[32], lc[32];
    if (t < 32) { ls[t] = 0.f; lc[t] = 0.f; }
    __syncthreads();
    float zn = 0.f, zo = 0.f, s = 0.f;
    #pragma unroll
    for (int sp = 0; sp < 4; ++sp) {
        const float* r = pPart + ((size_t)sp * P3 + q) * 3;
        zn += r[0]; zo += r[1]; s += r[2];
    }
    const float kl = s / zn - logf(zn) + logf(zo);
    const int b  = q / 256;
    const int pp = q % 256;
    const int h  = pp / 16;
    const int w  = pp % 16;
    const int lab = labels[b * 262144 + (h * 32) * 512 + (w * 32)];
    if ((unsigned)lab < (unsigned)ncls) {
        atomicAdd(&ls[lab], kl);
        atomicAdd(&lc[lab], 1.0f);
    }
    __syncthreads();
    if (t < 32 && lc[t] != 0.f) {
        atomicAdd(&clsSum[96 + t], ls[t]);
        atomicAdd(&clsCnt[96 + t], lc[t]);
    }
}

__global__ void k3_finalize(const float* __restrict__ clsSum,
                            const float* __restrict__ clsCnt,
                            const int* __restrict__ pNC,
                            const int* __restrict__ pNOC,
                            float* __restrict__ out) {
    const int t = threadIdx.x;              // 64 threads, one wave
    const int ncls = *pNC;
    const int nold = *pNOC;
    float acc = 0.f;
    for (int i = t; i < 128; i += 64) {
        const int s_ = i / 32;
        const int c  = i % 32;
        if (c < ncls) {
            const float cnt = clsCnt[i];
            const float sum = clsSum[i];
            const float mean = (cnt > 0.f) ? (sum / cnt) : 0.f;
            const float coef = (c == 0) ? (float)nold / (float)ncls
                                        : ((c <= nold) ? 1.f : 0.f);
            acc += (float)(s_ + 1) * coef * mean;   // WEIGHTS = 1,2,3,4
        }
    }
    #pragma unroll
    for (int off = 32; off > 0; off >>= 1) acc += __shfl_down(acc, off, 64);
    if (t == 0) out[0] = acc;
}

extern "C" void kernel_launch(void* const* d_in, const int* in_sizes, int n_in,
                              void* d_out, int out_size, void* d_ws, size_t ws_size,
                              hipStream_t stream) {
    const int* labels = (const int*)d_in[0];
    const float* fn[4];
    const float* fo[4];

    if (in_sizes[2] == in_sizes[1]) {       // interleaved (expected)
        fn[0] = (const float*)d_in[1]; fo[0] = (const float*)d_in[2];
        fn[1] = (const float*)d_in[3]; fo[1] = (const float*)d_in[4];
        fn[2] = (const float*)d_in[5]; fo[2] = (const float*)d_in[6];
        fn[3] = (const float*)d_in[7]; fo[3] = (const float*)d_in[8];
    } else {                                 // grouped (reference signature)
        fn[0] = (const float*)d_in[1]; fn[1] = (const float*)d_in[2];
        fn[2] = (const float*)d_in[3]; fn[3] = (const float*)d_in[4];
        fo[0] = (const float*)d_in[5]; fo[1] = (const float*)d_in[6];
        fo[2] = (const float*)d_in[7]; fo[3] = (const float*)d_in[8];
    }
    const int* pNC  = (const int*)d_in[9];
    const int* pNOC = (const int*)d_in[10];

    float* ws = (float*)d_ws;
    float* pPart  = ws;                     // 4*2048*3 = 24576 floats
    float* clsSum = ws + BINS_OFF;          // 128
    float* clsCnt = clsSum + 128;           // 128

    k0_zero<<<1, TPB, 0, stream>>>(clsSum);
    k1_fused<<<2048, TPB, 0, stream>>>(fn[0], fo[0], fn[1], fo[1],
                                       fn[2], fo[2], fn[3], fo[3],
                                       labels, pNC, pPart, clsSum, clsCnt);
    k2_scale3<<<P3 / TPB, TPB, 0, stream>>>(labels, pPart, clsSum, clsCnt, pNC);
    k3_finalize<<<1, 64, 0, stream>>>(clsSum, clsCnt, pNC, pNOC, (float*)d_out);
}